// Round 8
// baseline (3028.746 us; speedup 1.0000x reference)
//
#include <hip/hip_runtime.h>
#include <cstdint>

using u16 = unsigned short;
using u32 = uint32_t;
using u64 = unsigned long long;

typedef __bf16 bf16x8 __attribute__((ext_vector_type(8)));
typedef float  f32x4  __attribute__((ext_vector_type(4)));
typedef u32    uvec4  __attribute__((ext_vector_type(4)));

#define MFMA(a, b, c) __builtin_amdgcn_mfma_f32_16x16x32_bf16((a), (b), (c), 0, 0, 0)
#define SCOPE_AGT __HIP_MEMORY_SCOPE_AGENT

static __device__ __forceinline__ u64 ld_dev(const u64* p) {
  return __hip_atomic_load(p, __ATOMIC_RELAXED, SCOPE_AGT);
}
static __device__ __forceinline__ void st_dev(u64* p, u64 v) {
  __hip_atomic_store(p, v, __ATOMIC_RELAXED, SCOPE_AGT);
}
static __device__ __forceinline__ bf16x8 mk8(u64 lo, u64 hi) {
  union { u64 q[2]; bf16x8 v; } u;
  u.q[0] = lo; u.q[1] = hi;
  return u.v;
}

// ---------------- numeric helpers ----------------
static __device__ __forceinline__ u16 f2bf(float x) {
  u32 u = __float_as_uint(x);
  u32 r = (u + 0x7FFFu + ((u >> 16) & 1u)) >> 16;   // RNE
  return (u16)r;
}

static __device__ __forceinline__ u32 rotl32(u32 v, int s) {
  return (v << s) | (v >> (32 - s));
}

// JAX threefry2x32 (20 rounds)
static __device__ __forceinline__ void threefry2x32(u32 k0, u32 k1, u32 x0, u32 x1,
                                                    u32& o0, u32& o1) {
  u32 k2 = k0 ^ k1 ^ 0x1BD11BDAu;
  x0 += k0; x1 += k1;
  x0 += x1; x1 = rotl32(x1, 13); x1 ^= x0;
  x0 += x1; x1 = rotl32(x1, 15); x1 ^= x0;
  x0 += x1; x1 = rotl32(x1, 26); x1 ^= x0;
  x0 += x1; x1 = rotl32(x1, 6);  x1 ^= x0;
  x0 += k1; x1 += k2 + 1u;
  x0 += x1; x1 = rotl32(x1, 17); x1 ^= x0;
  x0 += x1; x1 = rotl32(x1, 29); x1 ^= x0;
  x0 += x1; x1 = rotl32(x1, 16); x1 ^= x0;
  x0 += x1; x1 = rotl32(x1, 24); x1 ^= x0;
  x0 += k2; x1 += k0 + 2u;
  x0 += x1; x1 = rotl32(x1, 13); x1 ^= x0;
  x0 += x1; x1 = rotl32(x1, 15); x1 ^= x0;
  x0 += x1; x1 = rotl32(x1, 26); x1 ^= x0;
  x0 += x1; x1 = rotl32(x1, 6);  x1 ^= x0;
  x0 += k0; x1 += k1 + 3u;
  x0 += x1; x1 = rotl32(x1, 17); x1 ^= x0;
  x0 += x1; x1 = rotl32(x1, 29); x1 ^= x0;
  x0 += x1; x1 = rotl32(x1, 16); x1 ^= x0;
  x0 += x1; x1 = rotl32(x1, 24); x1 ^= x0;
  x0 += k1; x1 += k2 + 4u;
  x0 += x1; x1 = rotl32(x1, 13); x1 ^= x0;
  x0 += x1; x1 = rotl32(x1, 15); x1 ^= x0;
  x0 += x1; x1 = rotl32(x1, 26); x1 ^= x0;
  x0 += x1; x1 = rotl32(x1, 6);  x1 ^= x0;
  x0 += k2; x1 += k0 + 5u;
  o0 = x0; o1 = x1;
}

// bits -> N(0,1) exactly like jax.random.normal(f32)
static __device__ __forceinline__ float bits_to_normal(u32 bits) {
  const float lo = __uint_as_float(0xBF7FFFFFu);
  float f = __uint_as_float((bits >> 9) | 0x3F800000u) - 1.0f;
  float x = fmaxf(lo, f * 2.0f + lo);
  float w = -logf((1.0f - x) * (1.0f + x));
  float p;
  if (w < 5.0f) {
    w -= 2.5f;
    p = 2.81022636e-08f;
    p = fmaf(p, w, 3.43273939e-07f);
    p = fmaf(p, w, -3.5233877e-06f);
    p = fmaf(p, w, -4.39150654e-06f);
    p = fmaf(p, w, 0.00021858087f);
    p = fmaf(p, w, -0.00125372503f);
    p = fmaf(p, w, -0.00417768164f);
    p = fmaf(p, w, 0.246640727f);
    p = fmaf(p, w, 1.50140941f);
  } else {
    w = sqrtf(w) - 3.0f;
    p = -0.000200214257f;
    p = fmaf(p, w, 0.000100950558f);
    p = fmaf(p, w, 0.00134934322f);
    p = fmaf(p, w, -0.00367342844f);
    p = fmaf(p, w, 0.00573950773f);
    p = fmaf(p, w, -0.0076224613f);
    p = fmaf(p, w, 0.00943887047f);
    p = fmaf(p, w, 1.00167406f);
    p = fmaf(p, w, 2.83297682f);
  }
  return 1.41421356f * p * x;
}

// ---------------- S1: fragment-pack weights (same layouts as r7) ----------------
__global__ __launch_bounds__(256) void s1_frag(
    const float* __restrict__ W1f, const float* __restrict__ W1g,
    const float* __restrict__ W2f, const float* __restrict__ W2g,
    u16* __restrict__ W1P, u16* __restrict__ W2P) {
  const int gid = blockIdx.x * 256 + threadIdx.x;
  const int f = gid >> 6, l = gid & 63;
  const int lr = l & 15, kg = l >> 4;
  u32 wbuf[4];
  if (f < 16384) {                       // W1P: (net*64+ct)*128 + q
    const int net = f >> 13, r = f & 8191, ct = r >> 7, q = r & 127;
    const float* __restrict__ src = net ? W1g : W1f;
    const int k = q * 32 + kg * 8, c = ct * 16 + lr;
    #pragma unroll
    for (int p = 0; p < 4; ++p) {
      u16 e0 = f2bf(src[(size_t)(k + 2 * p) * 1024 + c]);
      u16 e1 = f2bf(src[(size_t)(k + 2 * p + 1) * 1024 + c]);
      wbuf[p] = (u32)e0 | ((u32)e1 << 16);
    }
    *(uvec4*)(W1P + (size_t)f * 512 + l * 8) = *(uvec4*)wbuf;
  } else {                               // W2P: (net*256+ct16)*32 + q
    const int f2 = f - 16384;
    const int net = f2 >> 13, r = f2 & 8191, ct = r >> 5, q = r & 31;
    const float* __restrict__ src = net ? W2g : W2f;
    const int k = q * 32 + kg * 8, c = ct * 16 + lr;
    #pragma unroll
    for (int p = 0; p < 4; ++p) {
      u16 e0 = f2bf(src[(size_t)(k + 2 * p) * 4096 + c]);
      u16 e1 = f2bf(src[(size_t)(k + 2 * p + 1) * 4096 + c]);
      wbuf[p] = (u32)e0 | ((u32)e1 << 16);
    }
    *(uvec4*)(W2P + (size_t)f2 * 512 + l * 8) = *(uvec4*)wbuf;
  }
}

// ---------------- S2: t=0 output, APack init, counter zero ----------------
__global__ __launch_bounds__(256) void s2_init(
    const float* __restrict__ A0, u16* __restrict__ APack,
    u32* __restrict__ ctr, float* __restrict__ out) {
  const int gid = blockIdx.x * 256 + threadIdx.x;   // 262144
  const int n = gid & 4095, b = gid >> 12;
  const float a0 = A0[gid];
  const float sig = (n % 65 == 0) ? 0.0f : 1.0f / (1.0f + expf(-a0));
  #pragma unroll
  for (int s = 0; s < 4; ++s)
    out[((size_t)(s * 64) * 64 + b) * 4096 + n] = sig;
  if (gid < 32768) {                     // APack frag (m*128+q)
    const int fr = gid >> 6, l = gid & 63;
    const int m = fr >> 7, q = fr & 127;
    const int row = m * 16 + (l & 15);
    const int k = q * 32 + (l >> 4) * 8;
    u32 wbuf[4];
    #pragma unroll
    for (int p = 0; p < 4; ++p) {
      u16 e0 = f2bf(A0[(size_t)row * 4096 + k + 2 * p]);
      u16 e1 = f2bf(A0[(size_t)row * 4096 + k + 2 * p + 1]);
      wbuf[p] = (u32)e0 | ((u32)e1 << 16);
    }
    *(uvec4*)(APack + (size_t)fr * 512 + l * 8) = *(uvec4*)wbuf;
  }
  if (gid < 32) ctr[gid] = 0;            // MUST zero every launch (replays!)
}

// ---------------- fused persistent SDE (cooperative, custom barrier) ----------------
// 256 blocks x 512 thr. Weights via normal loads (L2-resident, bid%8 XCD-pinned);
// APack/HPack handoff via agent-scope (sc1/L3) atomics; A state in registers.
__global__ __launch_bounds__(512) void sde_fused(
    const float* __restrict__ A0, const float* __restrict__ tarr,
    const u16* __restrict__ W1P, const u16* __restrict__ W2P,
    const float* __restrict__ b1f, const float* __restrict__ b1g,
    const float* __restrict__ W1fv, const float* __restrict__ W1gv,
    const float* __restrict__ b2f, const float* __restrict__ b2g,
    u16* __restrict__ APack, u16* __restrict__ HPack,
    u32* __restrict__ ctr, float* __restrict__ out) {
  __shared__ union {
    struct { f32x4 ex[8][64]; u16 tile[2][16][16]; } pa;
    struct { f32x4 ex[8][64][4]; u16 tile[4][16][16]; } pb;
  } sm;
  const int bid = blockIdx.x, tix = threadIdx.x;
  const int wid = tix >> 6, lane = tix & 63;
  const int lr = lane & 15, lq = lane >> 4;

  // phase A roles: bid = mpA*64 + cgA  (same cgA -> same XCD for W1 reuse)
  const int cgA = bid & 63, mpA = bid >> 6;
  const int kkA = wid >> 1, ctlA = wid & 1;
  const int ctA = 2 * cgA + ctlA;        // 0..127 over f||g hidden ct16
  const int qHA = cgA & 31;
  // phase B roles: bid = mpB*128 + cgB
  const int cgB = bid & 127, mpB = bid >> 7;
  const int netW = wid >> 2, kkB = wid & 3;
  // phase-B reducer role (wid<4)
  const int mfR = wid & 1, ctlR = (wid >> 1) & 1;
  const int rowR = mpB * 32 + mfR * 16 + lq * 4;
  const int colR = cgB * 32 + ctlR * 16 + lr;

  f32x4 Ast;                             // A state (valid in wid<4)
  #pragma unroll
  for (int r = 0; r < 4; ++r) Ast[r] = A0[(size_t)(rowR + r) * 4096 + colR];

  const float dt = tarr[1] - tarr[0];
  const float sdt = sqrtf(dt);

  for (int step = 0; step < 63; ++step) {
    // ================= phase A: H = tanh(A @ W1 + b1 + t*w1last) =================
    {
      const u16* baseA = APack + ((size_t)(mpA * 128 + kkA * 32)) * 512 + lane * 8;
      const u16* baseW = W1P + ((size_t)(ctA * 128 + kkA * 32)) * 512 + lane * 8;
      u64 aL[8], aH[8];
      bf16x8 wv[8];
      #pragma unroll
      for (int d = 0; d < 8; ++d) {
        aL[d] = ld_dev((const u64*)(baseA + d * 512));
        aH[d] = ld_dev((const u64*)(baseA + d * 512) + 1);
        wv[d] = *(const bf16x8*)(baseW + d * 512);
      }
      f32x4 ac0 = {0.f,0.f,0.f,0.f}, ac1 = ac0, ac2 = ac0, ac3 = ac0;
      #pragma unroll
      for (int j = 0; j < 32; ++j) {
        const int s = j & 7;
        bf16x8 av = mk8(aL[s], aH[s]);
        if ((j & 3) == 0) ac0 = MFMA(av, wv[s], ac0);
        else if ((j & 3) == 1) ac1 = MFMA(av, wv[s], ac1);
        else if ((j & 3) == 2) ac2 = MFMA(av, wv[s], ac2);
        else ac3 = MFMA(av, wv[s], ac3);
        if (j + 8 < 32) {
          aL[s] = ld_dev((const u64*)(baseA + (j + 8) * 512));
          aH[s] = ld_dev((const u64*)(baseA + (j + 8) * 512) + 1);
          wv[s] = *(const bf16x8*)(baseW + (j + 8) * 512);
        }
      }
      sm.pa.ex[wid][lane] = (ac0 + ac1) + (ac2 + ac3);
      __syncthreads();
      if (wid < 2) {
        const int ctl = wid;
        const int ct = 2 * cgA + ctl, net = ct >> 6;
        f32x4 s0 = sm.pa.ex[ctl][lane] + sm.pa.ex[2 + ctl][lane]
                 + sm.pa.ex[4 + ctl][lane] + sm.pa.ex[6 + ctl][lane];
        const int ncl = (ct & 63) * 16 + lr;
        const float* __restrict__ b1 = net ? b1g : b1f;
        const float* __restrict__ wl = (net ? W1gv : W1fv) + (size_t)4096 * 1024;
        const float cc = b1[ncl] + tarr[step] * wl[ncl];
        #pragma unroll
        for (int r = 0; r < 4; ++r)
          sm.pa.tile[ctl][lq * 4 + r][lr] = f2bf(tanhf(s0[r] + cc));
      }
      __syncthreads();
      if (wid < 2 && lane < 32) {
        const int ctl = wid;
        const int ct = 2 * cgA + ctl, net = ct >> 6;
        const int row = lane & 15, kp = lane >> 4;
        const u16* src = &sm.pa.tile[ctl][row][kp * 8];
        u64 lo = *(const u64*)src, hi = *(const u64*)(src + 4);
        u16* dst = HPack + ((size_t)((net * 4 + mpA) * 32 + qHA)) * 512
                         + ((ctl * 2 + kp) * 16 + row) * 8;
        st_dev((u64*)dst, lo);
        st_dev((u64*)dst + 1, hi);
      }
      asm volatile("s_waitcnt vmcnt(0)" ::: "memory");
      __syncthreads();
      if (tix == 0) {
        const u32 tgt = 16u * ((u32)step * 2u + 1u);
        u32 old = __hip_atomic_fetch_add(&ctr[bid >> 4], 1u, __ATOMIC_RELAXED, SCOPE_AGT);
        if (old + 1u == tgt)
          __hip_atomic_fetch_add(&ctr[16], 1u, __ATOMIC_RELAXED, SCOPE_AGT);
        while (__hip_atomic_load(&ctr[16], __ATOMIC_RELAXED, SCOPE_AGT) < tgt)
          __builtin_amdgcn_s_sleep(4);
      }
      __syncthreads();
    }

    // ================= phase B: C = H @ W2 (f,g) -> SDE update =================
    {
      const u16* baseH0 = HPack + ((size_t)((netW * 4 + mpB * 2 + 0) * 32 + kkB * 8)) * 512 + lane * 8;
      const u16* baseH1 = HPack + ((size_t)((netW * 4 + mpB * 2 + 1) * 32 + kkB * 8)) * 512 + lane * 8;
      const u16* baseW0 = W2P + ((size_t)((netW * 256 + cgB * 2 + 0) * 32 + kkB * 8)) * 512 + lane * 8;
      const u16* baseW1 = W2P + ((size_t)((netW * 256 + cgB * 2 + 1) * 32 + kkB * 8)) * 512 + lane * 8;
      u64 h0L[4], h0H[4], h1L[4], h1H[4];
      bf16x8 w0v[4], w1v[4];
      #pragma unroll
      for (int d = 0; d < 4; ++d) {
        h0L[d] = ld_dev((const u64*)(baseH0 + d * 512));
        h0H[d] = ld_dev((const u64*)(baseH0 + d * 512) + 1);
        h1L[d] = ld_dev((const u64*)(baseH1 + d * 512));
        h1H[d] = ld_dev((const u64*)(baseH1 + d * 512) + 1);
        w0v[d] = *(const bf16x8*)(baseW0 + d * 512);
        w1v[d] = *(const bf16x8*)(baseW1 + d * 512);
      }
      f32x4 ac0 = {0.f,0.f,0.f,0.f}, ac1 = ac0, ac2 = ac0, ac3 = ac0;
      #pragma unroll
      for (int j = 0; j < 8; ++j) {
        const int s = j & 3;
        bf16x8 h0 = mk8(h0L[s], h0H[s]);
        bf16x8 h1 = mk8(h1L[s], h1H[s]);
        ac0 = MFMA(h0, w0v[s], ac0);
        ac1 = MFMA(h0, w1v[s], ac1);
        ac2 = MFMA(h1, w0v[s], ac2);
        ac3 = MFMA(h1, w1v[s], ac3);
        if (j + 4 < 8) {
          h0L[s] = ld_dev((const u64*)(baseH0 + (j + 4) * 512));
          h0H[s] = ld_dev((const u64*)(baseH0 + (j + 4) * 512) + 1);
          h1L[s] = ld_dev((const u64*)(baseH1 + (j + 4) * 512));
          h1H[s] = ld_dev((const u64*)(baseH1 + (j + 4) * 512) + 1);
          w0v[s] = *(const bf16x8*)(baseW0 + (j + 4) * 512);
          w1v[s] = *(const bf16x8*)(baseW1 + (j + 4) * 512);
        }
      }
      sm.pb.ex[wid][lane][0] = ac0;   // (mf0, cc0)
      sm.pb.ex[wid][lane][1] = ac1;   // (mf0, cc1)
      sm.pb.ex[wid][lane][2] = ac2;   // (mf1, cc0)
      sm.pb.ex[wid][lane][3] = ac3;   // (mf1, cc1)
      __syncthreads();
      if (wid < 4) {
        const int ai = mfR * 2 + ctlR;
        f32x4 CF = sm.pb.ex[0][lane][ai] + sm.pb.ex[1][lane][ai]
                 + sm.pb.ex[2][lane][ai] + sm.pb.ex[3][lane][ai];
        f32x4 CG = sm.pb.ex[4][lane][ai] + sm.pb.ex[5][lane][ai]
                 + sm.pb.ex[6][lane][ai] + sm.pb.ex[7][lane][ai];
        const int nc = colR;
        const float bfv = b2f[nc], bgv = b2g[nc];
        u32 k0s, k1s;
        threefry2x32(0u, 42u, 0u, (u32)step, k0s, k1s);
        #pragma unroll
        for (int r = 0; r < 4; ++r) {
          const int row = rowR + r;
          const float drift = CF[r] + bfv;
          const float graw = CG[r] + bgv;
          const float diff = fmaxf(graw, 0.0f) + log1pf(expf(-fabsf(graw)));
          u32 y0, y1;
          threefry2x32(k0s, k1s, 0u, (u32)(row * 4096 + nc), y0, y1);
          const float dw = bits_to_normal(y0 ^ y1) * sdt;
          const float an = Ast[r] + drift * dt + diff * dw;
          Ast[r] = an;
          sm.pb.tile[wid][lq * 4 + r][lr] = f2bf(an);
          const float sig = (nc % 65 == 0) ? 0.0f : 1.0f / (1.0f + expf(-an));
          #pragma unroll
          for (int smp = 0; smp < 4; ++smp)
            __builtin_nontemporal_store(
                sig, &out[((size_t)(smp * 64 + step + 1) * 64 + row) * 4096 + nc]);
        }
      }
      __syncthreads();
      if (wid < 4 && lane < 32) {
        const int row = lane & 15, kp = lane >> 4;
        const u16* src = &sm.pb.tile[wid][row][kp * 8];
        u64 lo = *(const u64*)src, hi = *(const u64*)(src + 4);
        const int mA = mpB * 2 + mfR;
        u16* dst = APack + ((size_t)(mA * 128 + cgB)) * 512
                         + ((ctlR * 2 + kp) * 16 + row) * 8;
        st_dev((u64*)dst, lo);
        st_dev((u64*)dst + 1, hi);
      }
      if (step < 62) {
        asm volatile("s_waitcnt vmcnt(0)" ::: "memory");
        __syncthreads();
        if (tix == 0) {
          const u32 tgt = 16u * ((u32)step * 2u + 2u);
          u32 old = __hip_atomic_fetch_add(&ctr[bid >> 4], 1u, __ATOMIC_RELAXED, SCOPE_AGT);
          if (old + 1u == tgt)
            __hip_atomic_fetch_add(&ctr[16], 1u, __ATOMIC_RELAXED, SCOPE_AGT);
          while (__hip_atomic_load(&ctr[16], __ATOMIC_RELAXED, SCOPE_AGT) < tgt)
            __builtin_amdgcn_s_sleep(4);
        }
        __syncthreads();
      }
    }
  }
}

// ---------------- launch ----------------
extern "C" void kernel_launch(void* const* d_in, const int* in_sizes, int n_in,
                              void* d_out, int out_size, void* d_ws, size_t ws_size,
                              hipStream_t stream) {
  const float* A0 = (const float*)d_in[0];
  const float* tarr = (const float*)d_in[1];
  const float* W1f = (const float*)d_in[2];
  const float* b1f = (const float*)d_in[3];
  const float* W2f = (const float*)d_in[4];
  const float* b2f = (const float*)d_in[5];
  const float* W1g = (const float*)d_in[6];
  const float* b1g = (const float*)d_in[7];
  const float* W2g = (const float*)d_in[8];
  const float* b2g = (const float*)d_in[9];
  float* outp = (float*)d_out;
  char* ws = (char*)d_ws;
  const size_t MB = 1024 * 1024;
  u16* W1P   = (u16*)(ws + 0 * MB);        // 16 MB frag-packed
  u16* W2P   = (u16*)(ws + 16 * MB);       // 16 MB
  u16* APack = (u16*)(ws + 32 * MB);       // 512 KB
  u16* HPack = (u16*)(ws + 33 * MB);       // 256 KB
  u32* ctr   = (u32*)(ws + 34 * MB);       // 32 u32 barrier counters

  s1_frag<<<dim3(8192), 256, 0, stream>>>(W1f, W1g, W2f, W2g, W1P, W2P);
  s2_init<<<dim3(1024), 256, 0, stream>>>(A0, APack, ctr, outp);

  void* kargs[] = {
    (void*)&A0, (void*)&tarr,
    (void*)&W1P, (void*)&W2P,
    (void*)&b1f, (void*)&b1g, (void*)&W1f, (void*)&W1g,
    (void*)&b2f, (void*)&b2g,
    (void*)&APack, (void*)&HPack, (void*)&ctr, (void*)&outp
  };
  hipLaunchCooperativeKernel((const void*)sde_fused, dim3(256), dim3(512),
                             kargs, 0, stream);
}

// Round 9
// 1926.577 us; speedup vs baseline: 1.5721x; 1.5721x over previous
//
#include <hip/hip_runtime.h>
#include <cstdint>

using u16 = unsigned short;
using u32 = uint32_t;
using u64 = unsigned long long;

typedef __bf16 bf16x8 __attribute__((ext_vector_type(8)));
typedef float  f32x4  __attribute__((ext_vector_type(4)));
typedef u32    uvec4  __attribute__((ext_vector_type(4)));

#define MFMA(a, b, c) __builtin_amdgcn_mfma_f32_16x16x32_bf16((a), (b), (c), 0, 0, 0)

// ---------------- numeric helpers ----------------
static __device__ __forceinline__ u16 f2bf(float x) {
  u32 u = __float_as_uint(x);
  u32 r = (u + 0x7FFFu + ((u >> 16) & 1u)) >> 16;   // RNE
  return (u16)r;
}

static __device__ __forceinline__ u32 rotl32(u32 v, int s) {
  return (v << s) | (v >> (32 - s));
}

// JAX threefry2x32 (20 rounds)
static __device__ __forceinline__ void threefry2x32(u32 k0, u32 k1, u32 x0, u32 x1,
                                                    u32& o0, u32& o1) {
  u32 k2 = k0 ^ k1 ^ 0x1BD11BDAu;
  x0 += k0; x1 += k1;
  x0 += x1; x1 = rotl32(x1, 13); x1 ^= x0;
  x0 += x1; x1 = rotl32(x1, 15); x1 ^= x0;
  x0 += x1; x1 = rotl32(x1, 26); x1 ^= x0;
  x0 += x1; x1 = rotl32(x1, 6);  x1 ^= x0;
  x0 += k1; x1 += k2 + 1u;
  x0 += x1; x1 = rotl32(x1, 17); x1 ^= x0;
  x0 += x1; x1 = rotl32(x1, 29); x1 ^= x0;
  x0 += x1; x1 = rotl32(x1, 16); x1 ^= x0;
  x0 += x1; x1 = rotl32(x1, 24); x1 ^= x0;
  x0 += k2; x1 += k0 + 2u;
  x0 += x1; x1 = rotl32(x1, 13); x1 ^= x0;
  x0 += x1; x1 = rotl32(x1, 15); x1 ^= x0;
  x0 += x1; x1 = rotl32(x1, 26); x1 ^= x0;
  x0 += x1; x1 = rotl32(x1, 6);  x1 ^= x0;
  x0 += k0; x1 += k1 + 3u;
  x0 += x1; x1 = rotl32(x1, 17); x1 ^= x0;
  x0 += x1; x1 = rotl32(x1, 29); x1 ^= x0;
  x0 += x1; x1 = rotl32(x1, 16); x1 ^= x0;
  x0 += x1; x1 = rotl32(x1, 24); x1 ^= x0;
  x0 += k1; x1 += k2 + 4u;
  x0 += x1; x1 = rotl32(x1, 13); x1 ^= x0;
  x0 += x1; x1 = rotl32(x1, 15); x1 ^= x0;
  x0 += x1; x1 = rotl32(x1, 26); x1 ^= x0;
  x0 += x1; x1 = rotl32(x1, 6);  x1 ^= x0;
  x0 += k2; x1 += k0 + 5u;
  o0 = x0; o1 = x1;
}

// bits -> N(0,1) exactly like jax.random.normal(f32)
static __device__ __forceinline__ float bits_to_normal(u32 bits) {
  const float lo = __uint_as_float(0xBF7FFFFFu);
  float f = __uint_as_float((bits >> 9) | 0x3F800000u) - 1.0f;
  float x = fmaxf(lo, f * 2.0f + lo);
  float w = -logf((1.0f - x) * (1.0f + x));
  float p;
  if (w < 5.0f) {
    w -= 2.5f;
    p = 2.81022636e-08f;
    p = fmaf(p, w, 3.43273939e-07f);
    p = fmaf(p, w, -3.5233877e-06f);
    p = fmaf(p, w, -4.39150654e-06f);
    p = fmaf(p, w, 0.00021858087f);
    p = fmaf(p, w, -0.00125372503f);
    p = fmaf(p, w, -0.00417768164f);
    p = fmaf(p, w, 0.246640727f);
    p = fmaf(p, w, 1.50140941f);
  } else {
    w = sqrtf(w) - 3.0f;
    p = -0.000200214257f;
    p = fmaf(p, w, 0.000100950558f);
    p = fmaf(p, w, 0.00134934322f);
    p = fmaf(p, w, -0.00367342844f);
    p = fmaf(p, w, 0.00573950773f);
    p = fmaf(p, w, -0.0076224613f);
    p = fmaf(p, w, 0.00943887047f);
    p = fmaf(p, w, 1.00167406f);
    p = fmaf(p, w, 2.83297682f);
  }
  return 1.41421356f * p * x;
}

// ---------------- S1: fragment-pack weights from f32 ----------------
// W1P: (net*64+ct)*128 + q ; W2P: (net*256+ct)*32 + q. Frag = 64 lanes x 16B,
// lane l = (col ct*16+(l&15), k q*32+(l>>4)*8)
__global__ __launch_bounds__(256) void s1_frag(
    const float* __restrict__ W1f, const float* __restrict__ W1g,
    const float* __restrict__ W2f, const float* __restrict__ W2g,
    u16* __restrict__ W1P, u16* __restrict__ W2P) {
  const int gid = blockIdx.x * 256 + threadIdx.x;
  const int f = gid >> 6, l = gid & 63;
  const int lr = l & 15, kg = l >> 4;
  u32 wbuf[4];
  if (f < 16384) {
    const int net = f >> 13, r = f & 8191, ct = r >> 7, q = r & 127;
    const float* __restrict__ src = net ? W1g : W1f;
    const int k = q * 32 + kg * 8, c = ct * 16 + lr;
    #pragma unroll
    for (int p = 0; p < 4; ++p) {
      u16 e0 = f2bf(src[(size_t)(k + 2 * p) * 1024 + c]);
      u16 e1 = f2bf(src[(size_t)(k + 2 * p + 1) * 1024 + c]);
      wbuf[p] = (u32)e0 | ((u32)e1 << 16);
    }
    *(uvec4*)(W1P + (size_t)f * 512 + l * 8) = *(uvec4*)wbuf;
  } else {
    const int f2 = f - 16384;
    const int net = f2 >> 13, r = f2 & 8191, ct = r >> 5, q = r & 31;
    const float* __restrict__ src = net ? W2g : W2f;
    const int k = q * 32 + kg * 8, c = ct * 16 + lr;
    #pragma unroll
    for (int p = 0; p < 4; ++p) {
      u16 e0 = f2bf(src[(size_t)(k + 2 * p) * 4096 + c]);
      u16 e1 = f2bf(src[(size_t)(k + 2 * p + 1) * 4096 + c]);
      wbuf[p] = (u32)e0 | ((u32)e1 << 16);
    }
    *(uvec4*)(W2P + (size_t)f2 * 512 + l * 8) = *(uvec4*)wbuf;
  }
}

// ---------------- S2: init A (f32), APack (frag bf16), t=0 output ----------------
__global__ __launch_bounds__(256) void s2_init(
    const float* __restrict__ A0, float* __restrict__ A, u16* __restrict__ APack,
    float* __restrict__ out) {
  const int gid = blockIdx.x * 256 + threadIdx.x;   // 262144
  const float a0 = A0[gid];
  A[gid] = a0;
  const int n = gid & 4095, b = gid >> 12;
  const float sig = (n % 65 == 0) ? 0.0f : 1.0f / (1.0f + expf(-a0));
  #pragma unroll
  for (int s = 0; s < 4; ++s)
    out[((size_t)(s * 64) * 64 + b) * 4096 + n] = sig;
  if (gid < 32768) {                     // APack: [m 4][q 128] frags
    const int fr = gid >> 6, l = gid & 63;
    const int m = fr >> 7, q = fr & 127;
    const int row = m * 16 + (l & 15);
    const int k = q * 32 + (l >> 4) * 8;
    u32 wbuf[4];
    #pragma unroll
    for (int p = 0; p < 4; ++p) {
      u16 e0 = f2bf(A0[(size_t)row * 4096 + k + 2 * p]);
      u16 e1 = f2bf(A0[(size_t)row * 4096 + k + 2 * p + 1]);
      wbuf[p] = (u32)e0 | ((u32)e1 << 16);
    }
    *(uvec4*)(APack + (size_t)fr * 512 + l * 8) = *(uvec4*)wbuf;
  }
}

// ---------------- dW pregen ----------------
__global__ __launch_bounds__(256) void dw_gen(
    const float* __restrict__ tarr, float* __restrict__ dst_base, int step_param) {
  const int bid = blockIdx.x, tix = threadIdx.x;
  const int step = (step_param < 0) ? (bid >> 5) : step_param;
  const int sub = (step_param < 0) ? (bid & 31) : bid;
  u32 k0, k1;
  threefry2x32(0u, 42u, 0u, (u32)step, k0, k1);
  const float sdt = sqrtf(tarr[1] - tarr[0]);
  float* dst = dst_base + ((step_param < 0) ? (size_t)step * 262144 : 0);
  #pragma unroll
  for (int j = 0; j < 32; ++j) {
    u32 e = (u32)(sub * 8192 + j * 256 + tix);
    u32 y0, y1;
    threefry2x32(k0, k1, 0u, e, y0, y1);
    dst[e] = bits_to_normal(y0 ^ y1) * sdt;
  }
}

// ---------------- G1: HPack = frag(tanh(A @ W1 + b1 + t*w1last)) ----------------
// grid 128 = rh(2 row-halves) x cg(64 col-groups of 32 hidden over f||g).
// 8 waves = ks(2 K-halves) x ctl(2) x m(2). Wave: 16x16 frag, 64 frag-chunks.
__global__ __launch_bounds__(512, 2) void g1_hidden(
    const u16* __restrict__ APack, const u16* __restrict__ W1P,
    u16* __restrict__ HPack,
    const float* __restrict__ b1f, const float* __restrict__ b1g,
    const float* __restrict__ W1fv, const float* __restrict__ W1gv,
    const float* __restrict__ tarr, int step) {
  __shared__ f32x4 ex[8][64];
  __shared__ __align__(16) u16 tile[2][2][16][16];   // [m][ctl][row][col]
  const int bid = blockIdx.x, tix = threadIdx.x;
  const int wid = tix >> 6, lane = tix & 63;
  const int lr = lane & 15, lq = lane >> 4;
  const int rh = bid >> 6, cg = bid & 63;
  const int net = cg >> 5, qh = cg & 31;
  const int m = wid & 1, ctl = (wid >> 1) & 1, ks = wid >> 2;
  const int p = rh * 2 + m;                       // m-panel 0..3
  const int ctw = (2 * cg + ctl) & 63;            // within-net ct16

  const u16* pa = APack + ((size_t)(p * 128 + ks * 64)) * 512 + lane * 8;
  const u16* pb = W1P + ((size_t)((net * 64 + ctw) * 128 + ks * 64)) * 512 + lane * 8;

  bf16x8 av[8], bv[8];
  #pragma unroll
  for (int d = 0; d < 8; ++d) {
    av[d] = *(const bf16x8*)(pa + d * 512);
    bv[d] = *(const bf16x8*)(pb + d * 512);
  }
  f32x4 acc = {0.f, 0.f, 0.f, 0.f};
  #pragma unroll
  for (int j = 0; j < 64; ++j) {
    const int s = j & 7;
    acc = MFMA(av[s], bv[s], acc);
    if (j + 8 < 64) {
      av[s] = *(const bf16x8*)(pa + (j + 8) * 512);
      bv[s] = *(const bf16x8*)(pb + (j + 8) * 512);
    }
  }
  ex[wid][lane] = acc;
  __syncthreads();

  // ks-reduce + bias + tanh (waves 0..3 = ks0)
  if (wid < 4) {
    f32x4 s0 = acc + ex[wid + 4][lane];
    const int nc = ctw * 16 + lr;
    const float* __restrict__ b1 = net ? b1g : b1f;
    const float* __restrict__ wl = (net ? W1gv : W1fv) + (size_t)4096 * 1024;
    const float cc = b1[nc] + tarr[step] * wl[nc];
    #pragma unroll
    for (int r = 0; r < 4; ++r)
      tile[m][ctl][lq * 4 + r][lr] = f2bf(tanhf(s0[r] + cc));
  }
  __syncthreads();

  // repack -> HPack frag [(net*4+p)*32 + qh]; waves 0..1 (m' = wid)
  if (wid < 2) {
    const int mm = wid;
    const int row = lane & 15, kp = (lane >> 4) & 1, ctl2 = lane >> 5;
    const u64 v = *(const u64*)&tile[mm][ctl2][row][kp * 8];
    const u64 v2 = *(const u64*)(&tile[mm][ctl2][row][kp * 8] + 4);
    u16* dst = HPack + ((size_t)((net * 4 + rh * 2 + mm) * 32 + qh)) * 512 + lane * 8;
    *(u64*)dst = v;
    *((u64*)dst + 1) = v2;
  }
}

// ---------------- G2: C = H @ W2 (f,g) -> SDE update -> A, APack, out ----------------
// grid 64 = cg (64 out-cols each). 8 waves = kk(2) x net(2) x cc(2).
// Wave: 4 m-frags x 2 ct16 x K-half (16 chunks) = 128 MFMA.
__global__ __launch_bounds__(512, 1) void g2_update(
    const u16* __restrict__ HPack, const u16* __restrict__ W2P,
    const float* __restrict__ b2f, const float* __restrict__ b2g,
    float* __restrict__ A, u16* __restrict__ APack,
    const float* __restrict__ dwstep, float* __restrict__ out,
    const float* __restrict__ tarr, int step) {
  __shared__ f32x4 exk[4][64][8];              // kk1 accs     (32 KB)
  __shared__ f32x4 exa[4][64][8];              // reduced accs (32 KB) [net*2+cc]
  __shared__ __align__(16) u16 tileA[4][16][64];  // 8 KB
  const int cg = blockIdx.x, tix = threadIdx.x;
  const int wid = tix >> 6, lane = tix & 63;
  const int lr = lane & 15, lq = lane >> 4;
  const int kk = wid >> 2, net = (wid >> 1) & 1, cc = wid & 1;

  const u16* hb[4];
  const u16* wb[2];
  #pragma unroll
  for (int mm = 0; mm < 4; ++mm)
    hb[mm] = HPack + ((size_t)((net * 4 + mm) * 32 + kk * 16)) * 512 + lane * 8;
  #pragma unroll
  for (int c = 0; c < 2; ++c)
    wb[c] = W2P + ((size_t)((net * 256 + cg * 4 + cc * 2 + c) * 32 + kk * 16)) * 512 + lane * 8;

  bf16x8 hv[4][4], wv[2][4];
  #pragma unroll
  for (int d = 0; d < 4; ++d) {
    #pragma unroll
    for (int mm = 0; mm < 4; ++mm) hv[mm][d] = *(const bf16x8*)(hb[mm] + d * 512);
    #pragma unroll
    for (int c = 0; c < 2; ++c) wv[c][d] = *(const bf16x8*)(wb[c] + d * 512);
  }
  f32x4 accs[4][2];
  #pragma unroll
  for (int mm = 0; mm < 4; ++mm) {
    accs[mm][0] = (f32x4){0.f, 0.f, 0.f, 0.f};
    accs[mm][1] = (f32x4){0.f, 0.f, 0.f, 0.f};
  }
  #pragma unroll
  for (int j = 0; j < 16; ++j) {
    const int s = j & 3;
    #pragma unroll
    for (int mm = 0; mm < 4; ++mm) {
      accs[mm][0] = MFMA(hv[mm][s], wv[0][s], accs[mm][0]);
      accs[mm][1] = MFMA(hv[mm][s], wv[1][s], accs[mm][1]);
    }
    if (j + 4 < 16) {
      #pragma unroll
      for (int mm = 0; mm < 4; ++mm) hv[mm][s] = *(const bf16x8*)(hb[mm] + (j + 4) * 512);
      #pragma unroll
      for (int c = 0; c < 2; ++c) wv[c][s] = *(const bf16x8*)(wb[c] + (j + 4) * 512);
    }
  }

  // stage 1: kk-reduce
  if (kk == 1) {
    #pragma unroll
    for (int mm = 0; mm < 4; ++mm) {
      exk[net * 2 + cc][lane][mm * 2 + 0] = accs[mm][0];
      exk[net * 2 + cc][lane][mm * 2 + 1] = accs[mm][1];
    }
  }
  __syncthreads();
  if (kk == 0) {
    #pragma unroll
    for (int mm = 0; mm < 4; ++mm) {
      accs[mm][0] += exk[net * 2 + cc][lane][mm * 2 + 0];
      accs[mm][1] += exk[net * 2 + cc][lane][mm * 2 + 1];
      exa[net * 2 + cc][lane][mm * 2 + 0] = accs[mm][0];
      exa[net * 2 + cc][lane][mm * 2 + 1] = accs[mm][1];
    }
  }
  __syncthreads();

  // stage 3: SDE update distributed over all 8 waves: (mu = wid>>1, ch = wid&1)
  {
    const float dt = tarr[1] - tarr[0];
    const int mu = wid >> 1, ch = wid & 1;
    #pragma unroll
    for (int cp = 0; cp < 2; ++cp) {
      const f32x4 CF = exa[0 * 2 + ch][lane][mu * 2 + cp];
      const f32x4 CG = exa[1 * 2 + ch][lane][mu * 2 + cp];
      const int nc = cg * 64 + ch * 32 + cp * 16 + lr;
      const float bfv = b2f[nc], bgv = b2g[nc];
      #pragma unroll
      for (int r = 0; r < 4; ++r) {
        const int row = mu * 16 + lq * 4 + r;
        const float drift = CF[r] + bfv;
        const float graw = CG[r] + bgv;
        const float diff = fmaxf(graw, 0.0f) + log1pf(expf(-fabsf(graw)));
        const int e = row * 4096 + nc;
        const float anew = A[e] + drift * dt + diff * dwstep[e];
        A[e] = anew;
        tileA[mu][lq * 4 + r][ch * 32 + cp * 16 + lr] = f2bf(anew);
        const float sig = (nc % 65 == 0) ? 0.0f : 1.0f / (1.0f + expf(-anew));
        #pragma unroll
        for (int s = 0; s < 4; ++s)
          __builtin_nontemporal_store(
              sig, &out[((size_t)(s * 64 + step + 1) * 64 + row) * 4096 + nc]);
      }
    }
  }
  __syncthreads();

  // stage 4: repack -> APack frags (m = wid>>1, qh = wid&1), q = cg*2+qh
  {
    const int mm = wid >> 1, qh = wid & 1;
    const int row = lane & 15, k8 = lane >> 4;
    const u16* src = &tileA[mm][row][qh * 32 + k8 * 8];
    const u64 v = *(const u64*)src;
    const u64 v2 = *(const u64*)(src + 4);
    u16* dst = APack + ((size_t)(mm * 128 + cg * 2 + qh)) * 512 + lane * 8;
    *(u64*)dst = v;
    *((u64*)dst + 1) = v2;
  }
}

// ---------------- launch ----------------
extern "C" void kernel_launch(void* const* d_in, const int* in_sizes, int n_in,
                              void* d_out, int out_size, void* d_ws, size_t ws_size,
                              hipStream_t stream) {
  const float* A0 = (const float*)d_in[0];
  const float* tarr = (const float*)d_in[1];
  const float* W1f = (const float*)d_in[2];
  const float* b1f = (const float*)d_in[3];
  const float* W2f = (const float*)d_in[4];
  const float* b2f = (const float*)d_in[5];
  const float* W1g = (const float*)d_in[6];
  const float* b1g = (const float*)d_in[7];
  const float* W2g = (const float*)d_in[8];
  const float* b2g = (const float*)d_in[9];
  float* out = (float*)d_out;
  char* ws = (char*)d_ws;
  const size_t MB = 1024 * 1024;
  u16* W1P   = (u16*)(ws + 0 * MB);        // 16 MB frag-packed
  u16* W2P   = (u16*)(ws + 16 * MB);       // 16 MB
  u16* APack = (u16*)(ws + 32 * MB);       // 512 KB
  u16* HPack = (u16*)(ws + 33 * MB);       // 256 KB
  float* A   = (float*)(ws + 34 * MB);     // 1 MB f32 state
  float* dwfb  = (float*)(ws + 35 * MB);   // 1 MB fallback
  float* dwall = (float*)(ws + 36 * MB);   // 63 MB pregen
  const bool pre = ws_size >= (size_t)100 * MB;

  s1_frag<<<dim3(8192), 256, 0, stream>>>(W1f, W1g, W2f, W2g, W1P, W2P);
  s2_init<<<dim3(1024), 256, 0, stream>>>(A0, A, APack, out);
  if (pre) dw_gen<<<dim3(63 * 32), 256, 0, stream>>>(tarr, dwall, -1);
  for (int i = 0; i < 63; ++i) {
    if (!pre) dw_gen<<<dim3(32), 256, 0, stream>>>(tarr, dwfb, i);
    g1_hidden<<<dim3(128), 512, 0, stream>>>(APack, W1P, HPack, b1f, b1g,
                                             W1f, W1g, tarr, i);
    const float* dwstep = pre ? (dwall + (size_t)i * 262144) : dwfb;
    g2_update<<<dim3(64), 512, 0, stream>>>(HPack, W2P, b2f, b2g,
                                            A, APack, dwstep, out, tarr, i);
  }
}

// Round 10
// 1786.347 us; speedup vs baseline: 1.6955x; 1.0785x over previous
//
#include <hip/hip_runtime.h>
#include <cstdint>

using u16 = unsigned short;
using u32 = uint32_t;
using u64 = unsigned long long;

typedef __bf16 bf16x8 __attribute__((ext_vector_type(8)));
typedef float  f32x4  __attribute__((ext_vector_type(4)));
typedef u32    uvec4  __attribute__((ext_vector_type(4)));

#define MFMA(a, b, c) __builtin_amdgcn_mfma_f32_16x16x32_bf16((a), (b), (c), 0, 0, 0)
#define SCOPE_AGT __HIP_MEMORY_SCOPE_AGENT

static __device__ __forceinline__ void st_dev(u64* p, u64 v) {
  __hip_atomic_store(p, v, __ATOMIC_RELAXED, SCOPE_AGT);
}

// ---------------- numeric helpers ----------------
static __device__ __forceinline__ u16 f2bf(float x) {
  u32 u = __float_as_uint(x);
  u32 r = (u + 0x7FFFu + ((u >> 16) & 1u)) >> 16;   // RNE
  return (u16)r;
}

static __device__ __forceinline__ u32 rotl32(u32 v, int s) {
  return (v << s) | (v >> (32 - s));
}

// JAX threefry2x32 (20 rounds)
static __device__ __forceinline__ void threefry2x32(u32 k0, u32 k1, u32 x0, u32 x1,
                                                    u32& o0, u32& o1) {
  u32 k2 = k0 ^ k1 ^ 0x1BD11BDAu;
  x0 += k0; x1 += k1;
  x0 += x1; x1 = rotl32(x1, 13); x1 ^= x0;
  x0 += x1; x1 = rotl32(x1, 15); x1 ^= x0;
  x0 += x1; x1 = rotl32(x1, 26); x1 ^= x0;
  x0 += x1; x1 = rotl32(x1, 6);  x1 ^= x0;
  x0 += k1; x1 += k2 + 1u;
  x0 += x1; x1 = rotl32(x1, 17); x1 ^= x0;
  x0 += x1; x1 = rotl32(x1, 29); x1 ^= x0;
  x0 += x1; x1 = rotl32(x1, 16); x1 ^= x0;
  x0 += x1; x1 = rotl32(x1, 24); x1 ^= x0;
  x0 += k2; x1 += k0 + 2u;
  x0 += x1; x1 = rotl32(x1, 13); x1 ^= x0;
  x0 += x1; x1 = rotl32(x1, 15); x1 ^= x0;
  x0 += x1; x1 = rotl32(x1, 26); x1 ^= x0;
  x0 += x1; x1 = rotl32(x1, 6);  x1 ^= x0;
  x0 += k0; x1 += k1 + 3u;
  x0 += x1; x1 = rotl32(x1, 17); x1 ^= x0;
  x0 += x1; x1 = rotl32(x1, 29); x1 ^= x0;
  x0 += x1; x1 = rotl32(x1, 16); x1 ^= x0;
  x0 += x1; x1 = rotl32(x1, 24); x1 ^= x0;
  x0 += k1; x1 += k2 + 4u;
  x0 += x1; x1 = rotl32(x1, 13); x1 ^= x0;
  x0 += x1; x1 = rotl32(x1, 15); x1 ^= x0;
  x0 += x1; x1 = rotl32(x1, 26); x1 ^= x0;
  x0 += x1; x1 = rotl32(x1, 6);  x1 ^= x0;
  x0 += k2; x1 += k0 + 5u;
  o0 = x0; o1 = x1;
}

// bits -> N(0,1) exactly like jax.random.normal(f32)
static __device__ __forceinline__ float bits_to_normal(u32 bits) {
  const float lo = __uint_as_float(0xBF7FFFFFu);
  float f = __uint_as_float((bits >> 9) | 0x3F800000u) - 1.0f;
  float x = fmaxf(lo, f * 2.0f + lo);
  float w = -logf((1.0f - x) * (1.0f + x));
  float p;
  if (w < 5.0f) {
    w -= 2.5f;
    p = 2.81022636e-08f;
    p = fmaf(p, w, 3.43273939e-07f);
    p = fmaf(p, w, -3.5233877e-06f);
    p = fmaf(p, w, -4.39150654e-06f);
    p = fmaf(p, w, 0.00021858087f);
    p = fmaf(p, w, -0.00125372503f);
    p = fmaf(p, w, -0.00417768164f);
    p = fmaf(p, w, 0.246640727f);
    p = fmaf(p, w, 1.50140941f);
  } else {
    w = sqrtf(w) - 3.0f;
    p = -0.000200214257f;
    p = fmaf(p, w, 0.000100950558f);
    p = fmaf(p, w, 0.00134934322f);
    p = fmaf(p, w, -0.00367342844f);
    p = fmaf(p, w, 0.00573950773f);
    p = fmaf(p, w, -0.0076224613f);
    p = fmaf(p, w, 0.00943887047f);
    p = fmaf(p, w, 1.00167406f);
    p = fmaf(p, w, 2.83297682f);
  }
  return 1.41421356f * p * x;
}

// ---------------- S1: fragment-pack weights from f32 (r7 layout) ----------------
__global__ __launch_bounds__(256) void s1_frag(
    const float* __restrict__ W1f, const float* __restrict__ W1g,
    const float* __restrict__ W2f, const float* __restrict__ W2g,
    u16* __restrict__ W1P, u16* __restrict__ W2P) {
  const int gid = blockIdx.x * 256 + threadIdx.x;
  const int f = gid >> 6, l = gid & 63;
  const int lr = l & 15, kg = l >> 4;
  u32 wbuf[4];
  if (f < 16384) {                       // W1P: (net*64+ct)*128 + q
    const int net = f >> 13, r = f & 8191, ct = r >> 7, q = r & 127;
    const float* __restrict__ src = net ? W1g : W1f;
    const int k = q * 32 + kg * 8, c = ct * 16 + lr;
    #pragma unroll
    for (int p = 0; p < 4; ++p) {
      u16 e0 = f2bf(src[(size_t)(k + 2 * p) * 1024 + c]);
      u16 e1 = f2bf(src[(size_t)(k + 2 * p + 1) * 1024 + c]);
      wbuf[p] = (u32)e0 | ((u32)e1 << 16);
    }
    *(uvec4*)(W1P + (size_t)f * 512 + l * 8) = *(uvec4*)wbuf;
  } else {                               // W2P: (net*256+ct16)*32 + q
    const int f2 = f - 16384;
    const int net = f2 >> 13, r = f2 & 8191, ct = r >> 5, q = r & 31;
    const float* __restrict__ src = net ? W2g : W2f;
    const int k = q * 32 + kg * 8, c = ct * 16 + lr;
    #pragma unroll
    for (int p = 0; p < 4; ++p) {
      u16 e0 = f2bf(src[(size_t)(k + 2 * p) * 4096 + c]);
      u16 e1 = f2bf(src[(size_t)(k + 2 * p + 1) * 4096 + c]);
      wbuf[p] = (u32)e0 | ((u32)e1 << 16);
    }
    *(uvec4*)(W2P + (size_t)f2 * 512 + l * 8) = *(uvec4*)wbuf;
  }
}

// ---------------- S2: t=0 output, APack[0] init, counters zero ----------------
__global__ __launch_bounds__(256) void s2_init(
    const float* __restrict__ A0, u16* __restrict__ APack,
    u32* __restrict__ ctr, float* __restrict__ out) {
  const int gid = blockIdx.x * 256 + threadIdx.x;   // 262144
  const int n = gid & 4095, b = gid >> 12;
  const float a0 = A0[gid];
  const float sig = (n % 65 == 0) ? 0.0f : 1.0f / (1.0f + expf(-a0));
  #pragma unroll
  for (int s = 0; s < 4; ++s)
    out[((size_t)(s * 64) * 64 + b) * 4096 + n] = sig;
  if (gid < 32768) {                     // APack[0]: [m 4][q 128] frags
    const int fr = gid >> 6, l = gid & 63;
    const int m = fr >> 7, q = fr & 127;
    const int row = m * 16 + (l & 15);
    const int k = q * 32 + (l >> 4) * 8;
    u32 wbuf[4];
    #pragma unroll
    for (int p = 0; p < 4; ++p) {
      u16 e0 = f2bf(A0[(size_t)row * 4096 + k + 2 * p]);
      u16 e1 = f2bf(A0[(size_t)row * 4096 + k + 2 * p + 1]);
      wbuf[p] = (u32)e0 | ((u32)e1 << 16);
    }
    *(uvec4*)(APack + (size_t)fr * 512 + l * 8) = *(uvec4*)wbuf;
  }
  if (gid < 32) ctr[gid] = 0;            // re-zero every launch (graph replays)
}

// ---------------- fused 63-step SDE (r7 geometry per phase, custom barrier) ----------------
__global__ __launch_bounds__(512) void sde_fused(
    const float* __restrict__ A0, const float* __restrict__ tarr,
    const u16* __restrict__ W1P, const u16* __restrict__ W2P,
    const float* __restrict__ b1f, const float* __restrict__ b1g,
    const float* __restrict__ W1fv, const float* __restrict__ W1gv,
    const float* __restrict__ b2f, const float* __restrict__ b2g,
    u16* __restrict__ APack, u16* __restrict__ HPack,
    u32* __restrict__ ctr, float* __restrict__ out) {
  __shared__ union {
    struct { f32x4 ex[8][64]; u16 tile[2][16][16]; } pa;
    struct { f32x4 ex[8][64][2]; u16 tile[2][16][32]; } pb;
  } sm;
  const int bid = blockIdx.x, tix = threadIdx.x;
  const int wid = tix >> 6, lane = tix & 63;
  const int lr = lane & 15, lq = lane >> 4;

  // phase A roles (== r7 g1_hidden, grid 256 = mp(2) x ctF(128))
  const int mp = bid >> 7, ctF = bid & 127;
  const int netA = ctF >> 6, ctA = ctF & 63;
  const int mA = wid & 1, ksA = wid >> 1;
  const int mGA = mp * 2 + mA;
  // phase B roles (== r7 g2_update, grid 256 = mp(2) x ct32(128))
  const int ct32 = bid & 127;
  const int ksB = wid >> 2, netB = (wid >> 1) & 1, mB = wid & 1;
  const int mGB = mp * 2 + mB;
  // phase B epilogue roles
  const int eM = wid & 1, eCf = (wid >> 1) & 1, eRh = wid >> 2;
  const int nc = ct32 * 32 + eCf * 16 + lr;

  // A-state in registers: 2 elements/thread, fixed ownership across all steps
  float Ast[2];
  #pragma unroll
  for (int ri = 0; ri < 2; ++ri) {
    const int row = mp * 32 + eM * 16 + lq * 4 + eRh * 2 + ri;
    Ast[ri] = A0[(size_t)row * 4096 + nc];
  }

  const float dt = tarr[1] - tarr[0];
  const float sdt = sqrtf(dt);

  for (int step = 0; step < 63; ++step) {
    // ================= phase A: HPack[step] = frag(tanh(A @ W1 + c)) =================
    {
      const u16* pa = APack + (size_t)step * 262144
                    + ((size_t)(mGA * 128 + ksA * 32)) * 512 + lane * 8;
      const u16* pb = W1P + ((size_t)((netA * 64 + ctA) * 128 + ksA * 32)) * 512 + lane * 8;
      bf16x8 av[8], bv[8];
      #pragma unroll
      for (int d = 0; d < 8; ++d) {
        av[d] = *(const bf16x8*)(pa + d * 512);
        bv[d] = *(const bf16x8*)(pb + d * 512);
      }
      f32x4 acc = {0.f, 0.f, 0.f, 0.f};
      #pragma unroll
      for (int j = 0; j < 32; ++j) {
        const int s = j & 7;
        acc = MFMA(av[s], bv[s], acc);
        if (j + 8 < 32) {
          av[s] = *(const bf16x8*)(pa + (j + 8) * 512);
          bv[s] = *(const bf16x8*)(pb + (j + 8) * 512);
        }
      }
      sm.pa.ex[wid][lane] = acc;
      __syncthreads();
      {
        const int gM = wid & 1, gR = wid >> 1;
        const f32x4 s0 = sm.pa.ex[gM][lane];
        const f32x4 s1 = sm.pa.ex[2 + gM][lane];
        const f32x4 s2 = sm.pa.ex[4 + gM][lane];
        const f32x4 s3 = sm.pa.ex[6 + gM][lane];
        const float ch = s0[gR] + s1[gR] + s2[gR] + s3[gR];
        const int ncl = ctA * 16 + lr;
        const float* __restrict__ b1 = netA ? b1g : b1f;
        const float* __restrict__ wl = (netA ? W1gv : W1fv) + (size_t)4096 * 1024;
        const float cc = b1[ncl] + tarr[step] * wl[ncl];
        sm.pa.tile[gM][lq * 4 + gR][lr] = f2bf(tanhf(ch + cc));
      }
      __syncthreads();
      if (wid < 2 && lane < 32) {
        const int mm = wid;
        const int row = lane & 15, kp = lane >> 4;
        const u16* src = &sm.pa.tile[mm][row][kp * 8];
        const u64 lo = *(const u64*)src;
        const u64 hi = *(const u64*)(src + 4);
        const int k8 = (ctA & 1) * 2 + kp;
        u16* dst = HPack + (size_t)step * 131072
                 + ((size_t)((netA * 4 + mp * 2 + mm) * 32 + (ctA >> 1))) * 512
                 + (k8 * 16 + row) * 8;
        st_dev((u64*)dst, lo);
        st_dev((u64*)dst + 1, hi);
      }
      asm volatile("s_waitcnt vmcnt(0)" ::: "memory");
      __syncthreads();
      if (tix == 0) {
        const u32 tgt = 16u * ((u32)step * 2u + 1u);
        u32 old = __hip_atomic_fetch_add(&ctr[bid >> 4], 1u, __ATOMIC_RELAXED, SCOPE_AGT);
        if (old + 1u == tgt)
          __hip_atomic_fetch_add(&ctr[16], 1u, __ATOMIC_RELAXED, SCOPE_AGT);
        while (__hip_atomic_load(&ctr[16], __ATOMIC_RELAXED, SCOPE_AGT) < tgt)
          __builtin_amdgcn_s_sleep(4);
      }
      __syncthreads();
    }

    // ================= phase B: C = H @ W2 (f,g) -> SDE update =================
    {
      const u16* ph = HPack + (size_t)step * 131072
                    + ((size_t)((netB * 4 + mGB) * 32 + ksB * 16)) * 512 + lane * 8;
      const u16* pw0 = W2P + ((size_t)((netB * 256 + ct32 * 2 + 0) * 32 + ksB * 16)) * 512 + lane * 8;
      const u16* pw1 = W2P + ((size_t)((netB * 256 + ct32 * 2 + 1) * 32 + ksB * 16)) * 512 + lane * 8;
      bf16x8 hv[8], w0[8], w1[8];
      #pragma unroll
      for (int d = 0; d < 8; ++d) {
        hv[d] = *(const bf16x8*)(ph + d * 512);
        w0[d] = *(const bf16x8*)(pw0 + d * 512);
        w1[d] = *(const bf16x8*)(pw1 + d * 512);
      }
      f32x4 a0 = {0.f, 0.f, 0.f, 0.f}, a1 = a0;
      #pragma unroll
      for (int j = 0; j < 16; ++j) {
        const int s = j & 7;
        a0 = MFMA(hv[s], w0[s], a0);
        a1 = MFMA(hv[s], w1[s], a1);
        if (j + 8 < 16) {
          hv[s] = *(const bf16x8*)(ph + (j + 8) * 512);
          w0[s] = *(const bf16x8*)(pw0 + (j + 8) * 512);
          w1[s] = *(const bf16x8*)(pw1 + (j + 8) * 512);
        }
      }
      sm.pb.ex[wid][lane][0] = a0;
      sm.pb.ex[wid][lane][1] = a1;
      __syncthreads();
      {
        const f32x4 CF = sm.pb.ex[eM][lane][eCf] + sm.pb.ex[4 + eM][lane][eCf];
        const f32x4 CG = sm.pb.ex[2 + eM][lane][eCf] + sm.pb.ex[6 + eM][lane][eCf];
        const float bfv = b2f[nc], bgv = b2g[nc];
        u32 k0s, k1s;
        threefry2x32(0u, 42u, 0u, (u32)step, k0s, k1s);
        #pragma unroll
        for (int ri = 0; ri < 2; ++ri) {
          const int r = eRh * 2 + ri;
          const int row = mp * 32 + eM * 16 + lq * 4 + r;
          const float drift = CF[r] + bfv;
          const float graw = CG[r] + bgv;
          const float diff = fmaxf(graw, 0.0f) + log1pf(expf(-fabsf(graw)));
          u32 y0, y1;
          threefry2x32(k0s, k1s, 0u, (u32)(row * 4096 + nc), y0, y1);
          const float dw = bits_to_normal(y0 ^ y1) * sdt;
          const float an = Ast[ri] + drift * dt + diff * dw;
          Ast[ri] = an;
          sm.pb.tile[eM][lq * 4 + r][eCf * 16 + lr] = f2bf(an);
          const float sig = (nc % 65 == 0) ? 0.0f : 1.0f / (1.0f + expf(-an));
          #pragma unroll
          for (int s = 0; s < 4; ++s)
            __builtin_nontemporal_store(
                sig, &out[((size_t)(s * 64 + step + 1) * 64 + row) * 4096 + nc]);
        }
      }
      __syncthreads();
      if (wid < 2) {
        const int mm = wid;
        const int row = lane & 15, kq = lane >> 4;
        const u16* src = &sm.pb.tile[mm][row][kq * 8];
        const u64 lo = *(const u64*)src;
        const u64 hi = *(const u64*)(src + 4);
        u16* dst = APack + (size_t)(step + 1) * 262144
                 + ((size_t)((mp * 2 + mm) * 128 + ct32)) * 512 + lane * 8;
        st_dev((u64*)dst, lo);
        st_dev((u64*)dst + 1, hi);
      }
      if (step < 62) {
        asm volatile("s_waitcnt vmcnt(0)" ::: "memory");
        __syncthreads();
        if (tix == 0) {
          const u32 tgt = 16u * ((u32)step * 2u + 2u);
          u32 old = __hip_atomic_fetch_add(&ctr[bid >> 4], 1u, __ATOMIC_RELAXED, SCOPE_AGT);
          if (old + 1u == tgt)
            __hip_atomic_fetch_add(&ctr[16], 1u, __ATOMIC_RELAXED, SCOPE_AGT);
          while (__hip_atomic_load(&ctr[16], __ATOMIC_RELAXED, SCOPE_AGT) < tgt)
            __builtin_amdgcn_s_sleep(4);
        }
        __syncthreads();
      }
    }
  }
}

// ---------------- launch ----------------
extern "C" void kernel_launch(void* const* d_in, const int* in_sizes, int n_in,
                              void* d_out, int out_size, void* d_ws, size_t ws_size,
                              hipStream_t stream) {
  const float* A0 = (const float*)d_in[0];
  const float* tarr = (const float*)d_in[1];
  const float* W1f = (const float*)d_in[2];
  const float* b1f = (const float*)d_in[3];
  const float* W2f = (const float*)d_in[4];
  const float* b2f = (const float*)d_in[5];
  const float* W1g = (const float*)d_in[6];
  const float* b1g = (const float*)d_in[7];
  const float* W2g = (const float*)d_in[8];
  const float* b2g = (const float*)d_in[9];
  float* outp = (float*)d_out;
  char* ws = (char*)d_ws;
  const size_t MB = 1024 * 1024;
  u16* W1P   = (u16*)(ws + 0 * MB);        // 16 MB frag-packed
  u16* W2P   = (u16*)(ws + 16 * MB);       // 16 MB
  u16* APack = (u16*)(ws + 32 * MB);       // 64 step-buffers x 512 KB = 32 MB
  u16* HPack = (u16*)(ws + 64 * MB);       // 63 step-buffers x 256 KB ~ 16 MB
  u32* ctr   = (u32*)(ws + 80 * MB);       // barrier counters

  s1_frag<<<dim3(8192), 256, 0, stream>>>(W1f, W1g, W2f, W2g, W1P, W2P);
  s2_init<<<dim3(1024), 256, 0, stream>>>(A0, APack, ctr, outp);

  void* kargs[] = {
    (void*)&A0, (void*)&tarr,
    (void*)&W1P, (void*)&W2P,
    (void*)&b1f, (void*)&b1g, (void*)&W1f, (void*)&W1g,
    (void*)&b2f, (void*)&b2g,
    (void*)&APack, (void*)&HPack, (void*)&ctr, (void*)&outp
  };
  hipLaunchCooperativeKernel((const void*)sde_fused, dim3(256), dim3(512),
                             kargs, 0, stream);
}

// Round 11
// 795.862 us; speedup vs baseline: 3.8056x; 2.2445x over previous
//
#include <hip/hip_runtime.h>
#include <cstdint>

using u16 = unsigned short;
using u32 = uint32_t;
using u64 = unsigned long long;

typedef __bf16 bf16x8 __attribute__((ext_vector_type(8)));
typedef float  f32x4  __attribute__((ext_vector_type(4)));
typedef u32    uvec4  __attribute__((ext_vector_type(4)));

typedef const __attribute__((address_space(1))) void GV;
typedef __attribute__((address_space(3))) void LV;

#define MFMA(a, b, c) __builtin_amdgcn_mfma_f32_16x16x32_bf16((a), (b), (c), 0, 0, 0)
#define SCOPE_AGT __HIP_MEMORY_SCOPE_AGENT

static __device__ __forceinline__ void gl_lds16(const u16* g, u16* l) {
  __builtin_amdgcn_global_load_lds((GV*)g, (LV*)l, 16, 0, 0);
}
static __device__ __forceinline__ void st_dev(u64* p, u64 v) {
  __hip_atomic_store(p, v, __ATOMIC_RELAXED, SCOPE_AGT);
}

// ---------------- numeric helpers ----------------
static __device__ __forceinline__ u16 f2bf(float x) {
  u32 u = __float_as_uint(x);
  u32 r = (u + 0x7FFFu + ((u >> 16) & 1u)) >> 16;   // RNE
  return (u16)r;
}

static __device__ __forceinline__ u32 rotl32(u32 v, int s) {
  return (v << s) | (v >> (32 - s));
}

// JAX threefry2x32 (20 rounds)
static __device__ __forceinline__ void threefry2x32(u32 k0, u32 k1, u32 x0, u32 x1,
                                                    u32& o0, u32& o1) {
  u32 k2 = k0 ^ k1 ^ 0x1BD11BDAu;
  x0 += k0; x1 += k1;
  x0 += x1; x1 = rotl32(x1, 13); x1 ^= x0;
  x0 += x1; x1 = rotl32(x1, 15); x1 ^= x0;
  x0 += x1; x1 = rotl32(x1, 26); x1 ^= x0;
  x0 += x1; x1 = rotl32(x1, 6);  x1 ^= x0;
  x0 += k1; x1 += k2 + 1u;
  x0 += x1; x1 = rotl32(x1, 17); x1 ^= x0;
  x0 += x1; x1 = rotl32(x1, 29); x1 ^= x0;
  x0 += x1; x1 = rotl32(x1, 16); x1 ^= x0;
  x0 += x1; x1 = rotl32(x1, 24); x1 ^= x0;
  x0 += k2; x1 += k0 + 2u;
  x0 += x1; x1 = rotl32(x1, 13); x1 ^= x0;
  x0 += x1; x1 = rotl32(x1, 15); x1 ^= x0;
  x0 += x1; x1 = rotl32(x1, 26); x1 ^= x0;
  x0 += x1; x1 = rotl32(x1, 6);  x1 ^= x0;
  x0 += k0; x1 += k1 + 3u;
  x0 += x1; x1 = rotl32(x1, 17); x1 ^= x0;
  x0 += x1; x1 = rotl32(x1, 29); x1 ^= x0;
  x0 += x1; x1 = rotl32(x1, 16); x1 ^= x0;
  x0 += x1; x1 = rotl32(x1, 24); x1 ^= x0;
  x0 += k1; x1 += k2 + 4u;
  x0 += x1; x1 = rotl32(x1, 13); x1 ^= x0;
  x0 += x1; x1 = rotl32(x1, 15); x1 ^= x0;
  x0 += x1; x1 = rotl32(x1, 26); x1 ^= x0;
  x0 += x1; x1 = rotl32(x1, 6);  x1 ^= x0;
  x0 += k2; x1 += k0 + 5u;
  o0 = x0; o1 = x1;
}

// bits -> N(0,1) exactly like jax.random.normal(f32)
static __device__ __forceinline__ float bits_to_normal(u32 bits) {
  const float lo = __uint_as_float(0xBF7FFFFFu);
  float f = __uint_as_float((bits >> 9) | 0x3F800000u) - 1.0f;
  float x = fmaxf(lo, f * 2.0f + lo);
  float w = -logf((1.0f - x) * (1.0f + x));
  float p;
  if (w < 5.0f) {
    w -= 2.5f;
    p = 2.81022636e-08f;
    p = fmaf(p, w, 3.43273939e-07f);
    p = fmaf(p, w, -3.5233877e-06f);
    p = fmaf(p, w, -4.39150654e-06f);
    p = fmaf(p, w, 0.00021858087f);
    p = fmaf(p, w, -0.00125372503f);
    p = fmaf(p, w, -0.00417768164f);
    p = fmaf(p, w, 0.246640727f);
    p = fmaf(p, w, 1.50140941f);
  } else {
    w = sqrtf(w) - 3.0f;
    p = -0.000200214257f;
    p = fmaf(p, w, 0.000100950558f);
    p = fmaf(p, w, 0.00134934322f);
    p = fmaf(p, w, -0.00367342844f);
    p = fmaf(p, w, 0.00573950773f);
    p = fmaf(p, w, -0.0076224613f);
    p = fmaf(p, w, 0.00943887047f);
    p = fmaf(p, w, 1.00167406f);
    p = fmaf(p, w, 2.83297682f);
  }
  return 1.41421356f * p * x;
}

// ---------------- S1: fragment-pack weights from f32 (r7 layout) ----------------
__global__ __launch_bounds__(256) void s1_frag(
    const float* __restrict__ W1f, const float* __restrict__ W1g,
    const float* __restrict__ W2f, const float* __restrict__ W2g,
    u16* __restrict__ W1P, u16* __restrict__ W2P) {
  const int gid = blockIdx.x * 256 + threadIdx.x;
  const int f = gid >> 6, l = gid & 63;
  const int lr = l & 15, kg = l >> 4;
  u32 wbuf[4];
  if (f < 16384) {                       // W1P: (net*64+ct)*128 + q
    const int net = f >> 13, r = f & 8191, ct = r >> 7, q = r & 127;
    const float* __restrict__ src = net ? W1g : W1f;
    const int k = q * 32 + kg * 8, c = ct * 16 + lr;
    #pragma unroll
    for (int p = 0; p < 4; ++p) {
      u16 e0 = f2bf(src[(size_t)(k + 2 * p) * 1024 + c]);
      u16 e1 = f2bf(src[(size_t)(k + 2 * p + 1) * 1024 + c]);
      wbuf[p] = (u32)e0 | ((u32)e1 << 16);
    }
    *(uvec4*)(W1P + (size_t)f * 512 + l * 8) = *(uvec4*)wbuf;
  } else {                               // W2P: (net*256+ct16)*32 + q
    const int f2 = f - 16384;
    const int net = f2 >> 13, r = f2 & 8191, ct = r >> 5, q = r & 31;
    const float* __restrict__ src = net ? W2g : W2f;
    const int k = q * 32 + kg * 8, c = ct * 16 + lr;
    #pragma unroll
    for (int p = 0; p < 4; ++p) {
      u16 e0 = f2bf(src[(size_t)(k + 2 * p) * 4096 + c]);
      u16 e1 = f2bf(src[(size_t)(k + 2 * p + 1) * 4096 + c]);
      wbuf[p] = (u32)e0 | ((u32)e1 << 16);
    }
    *(uvec4*)(W2P + (size_t)f2 * 512 + l * 8) = *(uvec4*)wbuf;
  }
}

// ---------------- S2: t=0 output, APack[0] init, counters zero ----------------
__global__ __launch_bounds__(256) void s2_init(
    const float* __restrict__ A0, u16* __restrict__ APack,
    u32* __restrict__ ctr, float* __restrict__ out) {
  const int gid = blockIdx.x * 256 + threadIdx.x;   // 262144
  const int n = gid & 4095, b = gid >> 12;
  const float a0 = A0[gid];
  const float sig = (n % 65 == 0) ? 0.0f : 1.0f / (1.0f + expf(-a0));
  #pragma unroll
  for (int s = 0; s < 4; ++s)
    out[((size_t)(s * 64) * 64 + b) * 4096 + n] = sig;
  if (gid < 32768) {                     // APack[0]: [m 4][q 128] frags
    const int fr = gid >> 6, l = gid & 63;
    const int m = fr >> 7, q = fr & 127;
    const int row = m * 16 + (l & 15);
    const int k = q * 32 + (l >> 4) * 8;
    u32 wbuf[4];
    #pragma unroll
    for (int p = 0; p < 4; ++p) {
      u16 e0 = f2bf(A0[(size_t)row * 4096 + k + 2 * p]);
      u16 e1 = f2bf(A0[(size_t)row * 4096 + k + 2 * p + 1]);
      wbuf[p] = (u32)e0 | ((u32)e1 << 16);
    }
    *(uvec4*)(APack + (size_t)fr * 512 + l * 8) = *(uvec4*)wbuf;
  }
  if (gid < 2048) ctr[gid] = 0;          // barrier lines; re-zero every launch
}

// ---------------- mp-half barrier (128 blocks), two-level, padded lines ----------------
static __device__ __forceinline__ void half_barrier(u32* ctr, int mp, int g, u32 tag) {
  __syncthreads();                        // all waves drained their stores (vmcnt before call)
  if (threadIdx.x == 0) {
    u32* arr  = ctr + (mp * 20 + g) * 32;
    u32* glob = ctr + (mp * 20 + 8) * 32;
    u32* flg  = ctr + (mp * 20 + 9 + g) * 32;
    u32 old = __hip_atomic_fetch_add(arr, 1u, __ATOMIC_RELAXED, SCOPE_AGT);
    if (old + 1u == 16u * tag) {
      u32 go = __hip_atomic_fetch_add(glob, 1u, __ATOMIC_RELAXED, SCOPE_AGT);
      if (go + 1u == 8u * tag) {
        #pragma unroll
        for (int i = 0; i < 8; ++i)
          __hip_atomic_store(ctr + (mp * 20 + 9 + i) * 32, tag, __ATOMIC_RELAXED, SCOPE_AGT);
      }
    }
    while (__hip_atomic_load(flg, __ATOMIC_RELAXED, SCOPE_AGT) < tag)
      __builtin_amdgcn_s_sleep(8);
  }
  __syncthreads();
}

// ---------------- fused 63-step SDE: W1 in VGPRs, W2 in LDS ----------------
__global__ __launch_bounds__(512) void sde_fused(
    const float* __restrict__ A0, const float* __restrict__ tarr,
    const u16* __restrict__ W1P, const u16* __restrict__ W2P,
    const float* __restrict__ b1f, const float* __restrict__ b1g,
    const float* __restrict__ W1fv, const float* __restrict__ W1gv,
    const float* __restrict__ b2f, const float* __restrict__ b2g,
    u16* __restrict__ APack, u16* __restrict__ HPack,
    u32* __restrict__ ctr, float* __restrict__ out) {
  extern __shared__ __align__(16) char smraw[];
  u16* w2l = (u16*)smraw;                                    // 128 KB W2 slice
  char* exraw = smraw + 131072;
  f32x4 (*paex)[64]     = (f32x4 (*)[64])exraw;              // 8 KB
  u16 (*patile)[16][16] = (u16 (*)[16][16])(exraw + 8192);   // 1 KB
  f32x4 (*pbex)[64][2]  = (f32x4 (*)[64][2])exraw;           // 16 KB (aliases paex)
  u16 (*pbtile)[16][32] = (u16 (*)[16][32])(exraw + 16384);  // 2 KB
  uint2* dwk = (uint2*)(exraw + 18432);                      // 504 B

  const int bid = blockIdx.x, tix = threadIdx.x;
  const int wid = tix >> 6, lane = tix & 63;
  const int lr = lane & 15, lq = lane >> 4;
  const int mp = bid >> 7;
  const int ctF = bid & 127;
  const int netA = ctF >> 6, ctA = ctF & 63;
  const int mA = wid & 1, ksA = wid >> 1;
  const int mGA = mp * 2 + mA;
  const int ct32 = bid & 127;
  const int ksB = wid >> 2, netB = (wid >> 1) & 1, mB = wid & 1;
  const int mGB = mp * 2 + mB;
  const int eM = wid & 1, eCf = (wid >> 1) & 1, eRh = wid >> 2;
  const int nc = ct32 * 32 + eCf * 16 + lr;
  const int g = (bid & 127) >> 4;

  // ---- prologue: stage W2 slice (128 frags) into LDS, layout f = net*64+c*32+ks*16+d
  #pragma unroll
  for (int i = 0; i < 16; ++i) {
    const int f = wid * 16 + i;
    const int nf = f >> 6, cf = (f >> 5) & 1, ksf = (f >> 4) & 1, df = f & 15;
    const u16* src = W2P
        + ((size_t)((nf * 256 + ct32 * 2 + cf) * 32 + ksf * 16 + df)) * 512 + lane * 8;
    gl_lds16(src, w2l + (size_t)f * 512);
  }
  if (tix < 63) {                        // dW step keys
    u32 y0, y1;
    threefry2x32(0u, 42u, 0u, (u32)tix, y0, y1);
    dwk[tix] = make_uint2(y0, y1);
  }
  // persistent W1 column slice: 32 frags = 128 VGPR
  bf16x8 wv[32];
  {
    const u16* pw = W1P + ((size_t)((netA * 64 + ctA) * 128 + ksA * 32)) * 512 + lane * 8;
    #pragma unroll
    for (int d = 0; d < 32; ++d) wv[d] = *(const bf16x8*)(pw + (size_t)d * 512);
  }
  // A-state in registers
  float Ast[2];
  #pragma unroll
  for (int ri = 0; ri < 2; ++ri) {
    const int row = mp * 32 + eM * 16 + lq * 4 + eRh * 2 + ri;
    Ast[ri] = A0[(size_t)row * 4096 + nc];
  }
  asm volatile("s_waitcnt vmcnt(0)" ::: "memory");
  __syncthreads();

  const float dt = tarr[1] - tarr[0];
  const float sdt = sqrtf(dt);

  for (int step = 0; step < 63; ++step) {
    // ===== phase A: HPack[step] = frag(tanh(A @ W1 + b1 + t*w1last)) =====
    {
      const u16* pa = APack + (size_t)step * 262144
                    + ((size_t)(mGA * 128 + ksA * 32)) * 512 + lane * 8;
      bf16x8 av[16];
      #pragma unroll
      for (int d = 0; d < 16; ++d) av[d] = *(const bf16x8*)(pa + (size_t)d * 512);
      f32x4 acc = {0.f, 0.f, 0.f, 0.f};
      #pragma unroll
      for (int j = 0; j < 32; ++j) {
        const int s = j & 15;
        acc = MFMA(av[s], wv[j], acc);
        if (j + 16 < 32) av[s] = *(const bf16x8*)(pa + (size_t)(j + 16) * 512);
      }
      paex[wid][lane] = acc;
      __syncthreads();
      {
        const int gM = wid & 1, gR = wid >> 1;
        const f32x4 s0 = paex[gM][lane];
        const f32x4 s1 = paex[2 + gM][lane];
        const f32x4 s2 = paex[4 + gM][lane];
        const f32x4 s3 = paex[6 + gM][lane];
        const float ch = s0[gR] + s1[gR] + s2[gR] + s3[gR];
        const int ncl = ctA * 16 + lr;
        const float* __restrict__ b1 = netA ? b1g : b1f;
        const float* __restrict__ wl = (netA ? W1gv : W1fv) + (size_t)4096 * 1024;
        const float cc = b1[ncl] + tarr[step] * wl[ncl];
        patile[gM][lq * 4 + gR][lr] = f2bf(tanhf(ch + cc));
      }
      __syncthreads();
      if (wid < 2 && lane < 32) {
        const int mm = wid;
        const int row = lane & 15, kp = lane >> 4;
        const u16* src = &patile[mm][row][kp * 8];
        const u64 lo = *(const u64*)src;
        const u64 hi = *(const u64*)(src + 4);
        const int k8 = (ctA & 1) * 2 + kp;
        u16* dst = HPack + (size_t)step * 131072
                 + ((size_t)((netA * 4 + mp * 2 + mm) * 32 + (ctA >> 1))) * 512
                 + (k8 * 16 + row) * 8;
        st_dev((u64*)dst, lo);
        st_dev((u64*)dst + 1, hi);
      }
      asm volatile("s_waitcnt vmcnt(0)" ::: "memory");
      half_barrier(ctr, mp, g, 2u * (u32)step + 1u);
    }

    // ===== phase B: C = H @ W2 (f,g) -> SDE update =====
    {
      const u16* ph = HPack + (size_t)step * 131072
                    + ((size_t)((netB * 4 + mGB) * 32 + ksB * 16)) * 512 + lane * 8;
      bf16x8 hv[8];
      #pragma unroll
      for (int d = 0; d < 8; ++d) hv[d] = *(const bf16x8*)(ph + (size_t)d * 512);
      const u16* wl0 = w2l + (size_t)(netB * 64 + ksB * 16) * 512 + lane * 8;
      const u16* wl1 = wl0 + (size_t)32 * 512;
      f32x4 a0 = {0.f, 0.f, 0.f, 0.f}, a1 = a0;
      #pragma unroll
      for (int j = 0; j < 16; ++j) {
        const int s = j & 7;
        const bf16x8 w0 = *(const bf16x8*)(wl0 + (size_t)j * 512);
        const bf16x8 w1 = *(const bf16x8*)(wl1 + (size_t)j * 512);
        a0 = MFMA(hv[s], w0, a0);
        a1 = MFMA(hv[s], w1, a1);
        if (j + 8 < 16) hv[s] = *(const bf16x8*)(ph + (size_t)(j + 8) * 512);
      }
      pbex[wid][lane][0] = a0;
      pbex[wid][lane][1] = a1;
      __syncthreads();
      float sg[2];
      {
        const f32x4 CF = pbex[eM][lane][eCf] + pbex[4 + eM][lane][eCf];
        const f32x4 CG = pbex[2 + eM][lane][eCf] + pbex[6 + eM][lane][eCf];
        const float bfv = b2f[nc], bgv = b2g[nc];
        const uint2 key = dwk[step];
        #pragma unroll
        for (int ri = 0; ri < 2; ++ri) {
          const int r = eRh * 2 + ri;
          const int row = mp * 32 + eM * 16 + lq * 4 + r;
          const float drift = CF[r] + bfv;
          const float graw = CG[r] + bgv;
          const float diff = fmaxf(graw, 0.0f) + log1pf(expf(-fabsf(graw)));
          u32 y0, y1;
          threefry2x32(key.x, key.y, 0u, (u32)(row * 4096 + nc), y0, y1);
          const float dw = bits_to_normal(y0 ^ y1) * sdt;
          const float an = Ast[ri] + drift * dt + diff * dw;
          Ast[ri] = an;
          pbtile[eM][lq * 4 + r][eCf * 16 + lr] = f2bf(an);
          sg[ri] = (nc % 65 == 0) ? 0.0f : 1.0f / (1.0f + expf(-an));
        }
      }
      __syncthreads();
      if (wid < 2) {
        const int mm = wid;
        const int row = lane & 15, kq = lane >> 4;
        const u16* src = &pbtile[mm][row][kq * 8];
        const u64 lo = *(const u64*)src;
        const u64 hi = *(const u64*)(src + 4);
        u16* dst = APack + (size_t)(step + 1) * 262144
                 + ((size_t)((mp * 2 + mm) * 128 + ct32)) * 512 + lane * 8;
        st_dev((u64*)dst, lo);
        st_dev((u64*)dst + 1, hi);
      }
      asm volatile("s_waitcnt vmcnt(0)" ::: "memory");
      // deferred output stores: overlap the barrier wait
      #pragma unroll
      for (int ri = 0; ri < 2; ++ri) {
        const int row = mp * 32 + eM * 16 + lq * 4 + eRh * 2 + ri;
        #pragma unroll
        for (int s = 0; s < 4; ++s)
          __builtin_nontemporal_store(
              sg[ri], &out[((size_t)(s * 64 + step + 1) * 64 + row) * 4096 + nc]);
      }
      if (step < 62) half_barrier(ctr, mp, g, 2u * (u32)step + 2u);
    }
  }
}

// ---------------- launch ----------------
extern "C" void kernel_launch(void* const* d_in, const int* in_sizes, int n_in,
                              void* d_out, int out_size, void* d_ws, size_t ws_size,
                              hipStream_t stream) {
  const float* A0 = (const float*)d_in[0];
  const float* tarr = (const float*)d_in[1];
  const float* W1f = (const float*)d_in[2];
  const float* b1f = (const float*)d_in[3];
  const float* W2f = (const float*)d_in[4];
  const float* b2f = (const float*)d_in[5];
  const float* W1g = (const float*)d_in[6];
  const float* b1g = (const float*)d_in[7];
  const float* W2g = (const float*)d_in[8];
  const float* b2g = (const float*)d_in[9];
  float* outp = (float*)d_out;
  char* ws = (char*)d_ws;
  const size_t MB = 1024 * 1024;
  u16* W1P   = (u16*)(ws + 0 * MB);        // 16 MB frag-packed
  u16* W2P   = (u16*)(ws + 16 * MB);       // 16 MB
  u16* APack = (u16*)(ws + 32 * MB);       // 64 step-buffers x 512 KB = 32 MB
  u16* HPack = (u16*)(ws + 64 * MB);       // 63 step-buffers x 256 KB ~ 16 MB
  u32* ctr   = (u32*)(ws + 80 * MB);       // padded barrier lines (8 KB)

  s1_frag<<<dim3(8192), 256, 0, stream>>>(W1f, W1g, W2f, W2g, W1P, W2P);
  s2_init<<<dim3(1024), 256, 0, stream>>>(A0, APack, ctr, outp);

  void* kargs[] = {
    (void*)&A0, (void*)&tarr,
    (void*)&W1P, (void*)&W2P,
    (void*)&b1f, (void*)&b1g, (void*)&W1f, (void*)&W1g,
    (void*)&b2f, (void*)&b2g,
    (void*)&APack, (void*)&HPack, (void*)&ctr, (void*)&outp
  };
  hipLaunchCooperativeKernel((const void*)sde_fused, dim3(256), dim3(512),
                             kargs, 150016, stream);
}